// Round 1
// baseline (154.873 us; speedup 1.0000x reference)
//
#include <hip/hip_runtime.h>

// MLPKAN: two KAN layers. Each subnet: scalar x -> H=2 -> H=2 -> scalar, ReLU.
// Layer0: in=64, out=64 (N=4096 subnets). Layer1: in=64, out=16 (N=1024).
// B = 16384. All fp32.
//
// Layout: lanes = output index o (coalesced weight loads, n = i*out + o),
// batch b wave-uniform -> x[b,i] is a scalar broadcast load.

#define BATCH 16384
#define IN0   64
#define OUT0  64
#define IN1   64
#define OUT1  16

constexpr int NB0 = 16;  // batches per wave, layer 0
constexpr int NB1 = 8;   // batches per (wave x bsub), layer 1

__global__ __launch_bounds__(256) void kan_l0(
    const float* __restrict__ x,
    const float* __restrict__ W1, const float* __restrict__ b1,
    const float* __restrict__ W2, const float* __restrict__ b2,
    const float* __restrict__ W3, const float* __restrict__ b3,
    float* __restrict__ hbuf)
{
    const int lane = threadIdx.x & 63;
    const int wave = threadIdx.x >> 6;
    const int o    = lane;
    const int b0   = blockIdx.x * (4 * NB0) + wave * NB0;

    float acc[NB0];
#pragma unroll
    for (int j = 0; j < NB0; ++j) acc[j] = 0.f;
    float bsum = 0.f;

    for (int i = 0; i < IN0; ++i) {
        const int n = i * OUT0 + o;
        const float2 w1 = *(const float2*)(W1 + 2 * n);
        const float2 c1 = *(const float2*)(b1 + 2 * n);
        const float4 w2 = *(const float4*)(W2 + 4 * n);
        const float2 c2 = *(const float2*)(b2 + 2 * n);
        const float2 w3 = *(const float2*)(W3 + 2 * n);
        bsum += b3[n];
#pragma unroll
        for (int j = 0; j < NB0; ++j) {
            const float xv = x[(b0 + j) * IN0 + i];   // wave-uniform -> s_load
            float m0 = fmaxf(fmaf(xv, w1.x, c1.x), 0.f);
            float m1 = fmaxf(fmaf(xv, w1.y, c1.y), 0.f);
            float t0 = fmaxf(fmaf(w2.x, m0, fmaf(w2.y, m1, c2.x)), 0.f);
            float t1 = fmaxf(fmaf(w2.z, m0, fmaf(w2.w, m1, c2.y)), 0.f);
            acc[j] = fmaf(w3.x, t0, acc[j]);
            acc[j] = fmaf(w3.y, t1, acc[j]);
        }
    }
#pragma unroll
    for (int j = 0; j < NB0; ++j)
        hbuf[(b0 + j) * OUT0 + o] = acc[j] + bsum;  // coalesced (lanes = o)
}

__global__ __launch_bounds__(256) void kan_l1(
    const float* __restrict__ h,
    const float* __restrict__ W1, const float* __restrict__ b1,
    const float* __restrict__ W2, const float* __restrict__ b2,
    const float* __restrict__ W3, const float* __restrict__ b3,
    float* __restrict__ out)
{
    const int lane = threadIdx.x & 63;
    const int wave = threadIdx.x >> 6;
    const int o    = lane & 15;      // 16 outputs
    const int bs   = lane >> 4;      // 4 batch sub-groups per wave
    const int b0   = blockIdx.x * (4 * 4 * NB1) + wave * (4 * NB1) + bs * NB1;

    float acc[NB1];
#pragma unroll
    for (int j = 0; j < NB1; ++j) acc[j] = 0.f;
    float bsum = 0.f;

    for (int i = 0; i < IN1; ++i) {
        const int n = i * OUT1 + o;
        const float2 w1 = *(const float2*)(W1 + 2 * n);
        const float2 c1 = *(const float2*)(b1 + 2 * n);
        const float4 w2 = *(const float4*)(W2 + 4 * n);
        const float2 c2 = *(const float2*)(b2 + 2 * n);
        const float2 w3 = *(const float2*)(W3 + 2 * n);
        bsum += b3[n];
#pragma unroll
        for (int j = 0; j < NB1; ++j) {
            const float xv = h[(b0 + j) * IN1 + i];  // 4 distinct addrs/wave, L2-hot
            float m0 = fmaxf(fmaf(xv, w1.x, c1.x), 0.f);
            float m1 = fmaxf(fmaf(xv, w1.y, c1.y), 0.f);
            float t0 = fmaxf(fmaf(w2.x, m0, fmaf(w2.y, m1, c2.x)), 0.f);
            float t1 = fmaxf(fmaf(w2.z, m0, fmaf(w2.w, m1, c2.y)), 0.f);
            acc[j] = fmaf(w3.x, t0, acc[j]);
            acc[j] = fmaf(w3.y, t1, acc[j]);
        }
    }
#pragma unroll
    for (int j = 0; j < NB1; ++j)
        out[(b0 + j) * OUT1 + o] = acc[j] + bsum;
}

extern "C" void kernel_launch(void* const* d_in, const int* in_sizes, int n_in,
                              void* d_out, int out_size, void* d_ws, size_t ws_size,
                              hipStream_t stream) {
    const float* x     = (const float*)d_in[0];
    const float* l0_W1 = (const float*)d_in[1];
    const float* l0_b1 = (const float*)d_in[2];
    const float* l0_W2 = (const float*)d_in[3];
    const float* l0_b2 = (const float*)d_in[4];
    const float* l0_W3 = (const float*)d_in[5];
    const float* l0_b3 = (const float*)d_in[6];
    const float* l1_W1 = (const float*)d_in[7];
    const float* l1_b1 = (const float*)d_in[8];
    const float* l1_W2 = (const float*)d_in[9];
    const float* l1_b2 = (const float*)d_in[10];
    const float* l1_W3 = (const float*)d_in[11];
    const float* l1_b3 = (const float*)d_in[12];

    float* hbuf = (float*)d_ws;                 // [BATCH, 64] fp32 = 4 MB
    float* outp = (float*)d_out;                // [BATCH, 16] fp32

    dim3 blk(256);
    dim3 grid0(BATCH / (4 * NB0));              // 256 blocks
    dim3 grid1(BATCH / (16 * NB1));             // 128 blocks

    hipLaunchKernelGGL(kan_l0, grid0, blk, 0, stream,
                       x, l0_W1, l0_b1, l0_W2, l0_b2, l0_W3, l0_b3, hbuf);
    hipLaunchKernelGGL(kan_l1, grid1, blk, 0, stream,
                       hbuf, l1_W1, l1_b1, l1_W2, l1_b2, l1_W3, l1_b3, outp);
}